// Round 4
// baseline (270.870 us; speedup 1.0000x reference)
//
#include <hip/hip_runtime.h>
#include <hip/hip_bf16.h>
#include <math.h>

// Problem constants: S=4, B=1, C=128, h=w=d=10 -> N=1000, L=4000, nL=2, H=8, Dh=16
#define LL 4000
#define CC 128
#define NN 1000
#define NLAYER 2
#define KSPLIT 4
#define NTILE 125                       // 4000 / 32 key-tiles
#define SCLOG2 0.36067376022224085f    // 0.25 * log2(e)

typedef __attribute__((ext_vector_type(4))) short bf16x4;
typedef __attribute__((ext_vector_type(8))) short short8;
typedef __attribute__((ext_vector_type(4))) float f32x4;

__device__ __forceinline__ short bf16rne(float f) {
    return __builtin_bit_cast(short, __float2bfloat16(f));
}

// ---------------------------------------------------------------------------
// tokenize: z[S,1,C,N] + seq_embed[S,C] -> tok[L,C] (f32) + tokb (bf16)
__global__ void tokenize_kernel(const float* __restrict__ z,
                                const float* __restrict__ se,
                                float* __restrict__ tok,
                                short* __restrict__ tokb) {
    int idx = blockIdx.x * blockDim.x + threadIdx.x;
    if (idx >= LL * CC) return;
    int c = idx & (CC - 1);
    int t = idx >> 7;
    int s = t / NN;
    int n = t - s * NN;
    float v = z[(s * CC + c) * NN + n] + se[s * CC + c];
    tok[idx] = v;
    tokb[idx] = bf16rne(v);
}

// detokenize: tok[L,C] -> out[(s*C+c)*N + n]
__global__ void detok_kernel(const float* __restrict__ tok,
                             float* __restrict__ out) {
    int idx = blockIdx.x * blockDim.x + threadIdx.x;
    if (idx >= LL * CC) return;
    int n = idx % NN;
    int sc = idx / NN;
    int c = sc & (CC - 1);
    int s = sc >> 7;
    out[idx] = tok[(s * NN + n) * CC + c];
}

// kb[l*L + j] = beta[l] * log2(r[j/N])   (log2-domain; row term softmax-invariant)
__global__ void kbias_kernel(const float* __restrict__ r,
                             const float* __restrict__ beta,
                             float* __restrict__ kb) {
    int idx = blockIdx.x * blockDim.x + threadIdx.x;
    if (idx >= NLAYER * LL) return;
    int l = idx / LL;
    int j = idx - l * LL;
    kb[idx] = beta[l] * __log2f(r[j / NN]);
}

// ---------------------------------------------------------------------------
// weight prep: bf16 + transpose -> Wt[N][K]
__global__ void prep_weights(const float* __restrict__ Wq, const float* __restrict__ Wk,
                             const float* __restrict__ Wv, const float* __restrict__ Wp,
                             const float* __restrict__ w1, const float* __restrict__ w2,
                             short* __restrict__ wt8, short* __restrict__ w1t,
                             short* __restrict__ w2t) {
    int idx = blockIdx.x * blockDim.x + threadIdx.x;
    if (idx < 8 * 16384) {
        int m = idx >> 14, i = idx & 16383;
        int n = i >> 7, k = i & 127;
        const float* src = (m < 2) ? Wq + (size_t)m * 16384
                         : (m < 4) ? Wk + (size_t)(m - 2) * 16384
                         : (m < 6) ? Wv + (size_t)(m - 4) * 16384
                                   : Wp + (size_t)(m - 6) * 16384;
        wt8[idx] = bf16rne(src[k * 128 + n]);
    } else if (idx < 8 * 16384 + 65536) {
        int i = idx - 8 * 16384;
        int n = i >> 7, k = i & 127;
        w1t[i] = bf16rne(w1[(size_t)k * 512 + n]);
    } else if (idx < 8 * 16384 + 2 * 65536) {
        int i = idx - 8 * 16384 - 65536;
        int n = i >> 9, k = i & 511;
        w2t[i] = bf16rne(w2[(size_t)k * 128 + n]);
    }
}

// ---------------------------------------------------------------------------
// MFMA GEMM body: out[M,N] = act(A[M,K] @ Wt[N,K]^T + bias)
// flags: 1 = bf16 out, 2 = exact GELU, 4 = bf16 TRANSPOSED out (out[N][M])
__device__ __forceinline__ void gemm_body(
        const short* __restrict__ A, const short* __restrict__ Wt,
        const float* __restrict__ bias, void* __restrict__ outp,
        int M, int K, int N, int flags, int row0, int col0) {
    __shared__ short Al[16][136];
    __shared__ short Wl[128][136];
    const int tid = threadIdx.x;
    const int lane = tid & 63;
    const int w = tid >> 6;
    const int lq = lane & 15, g = lane >> 4;

    f32x4 acc[2] = {{0.f,0.f,0.f,0.f},{0.f,0.f,0.f,0.f}};

    for (int kc = 0; kc < K; kc += 128) {
        {   // stage A tile: 16 x 128 shorts
            int r = tid >> 4, c = (tid & 15) * 8;
            *(short8*)&Al[r][c] = *(const short8*)(A + (size_t)(row0 + r) * K + kc + c);
        }
        {   // stage W tile: 128 x 128 shorts
            int c = (tid & 15) * 8;
            int nb = tid >> 4;
            #pragma unroll
            for (int i = 0; i < 8; ++i) {
                int n = nb + i * 16;
                *(short8*)&Wl[n][c] = *(const short8*)(Wt + (size_t)(col0 + n) * K + kc + c);
            }
        }
        __syncthreads();
        bf16x4 af[8];
        #pragma unroll
        for (int ks = 0; ks < 8; ++ks)
            af[ks] = *(const bf16x4*)&Al[lq][ks * 16 + g * 4];
        #pragma unroll
        for (int ct = 0; ct < 2; ++ct) {
            int n = (w * 2 + ct) * 16 + lq;
            #pragma unroll
            for (int ks = 0; ks < 8; ++ks) {
                bf16x4 bfr = *(const bf16x4*)&Wl[n][ks * 16 + g * 4];
                acc[ct] = __builtin_amdgcn_mfma_f32_16x16x16bf16_1k(af[ks], bfr, acc[ct], 0, 0, 0);
            }
        }
        __syncthreads();
    }
    #pragma unroll
    for (int ct = 0; ct < 2; ++ct) {
        int col = col0 + (w * 2 + ct) * 16 + lq;
        float bv = bias ? bias[col] : 0.f;
        float v[4];
        #pragma unroll
        for (int r = 0; r < 4; ++r) {
            v[r] = acc[ct][r] + bv;
            if (flags & 2) v[r] = 0.5f * v[r] * (1.f + erff(v[r] * 0.70710678118654752f));
        }
        if (flags & 4) {            // transposed bf16: out[col][row], vector store
            bf16x4 res = {bf16rne(v[0]), bf16rne(v[1]), bf16rne(v[2]), bf16rne(v[3])};
            *(bf16x4*)((short*)outp + (size_t)col * M + row0 + g * 4) = res;
        } else if (flags & 1) {
            #pragma unroll
            for (int r = 0; r < 4; ++r)
                ((short*)outp)[(size_t)(row0 + g * 4 + r) * N + col] = bf16rne(v[r]);
        } else {
            #pragma unroll
            for (int r = 0; r < 4; ++r)
                ((float*)outp)[(size_t)(row0 + g * 4 + r) * N + col] = v[r];
        }
    }
}

__global__ __launch_bounds__(256) void mfma_gemm(
        const short* __restrict__ A, const short* __restrict__ Wt,
        const float* __restrict__ bias, void* __restrict__ outp,
        int M, int K, int N, int flags) {
    gemm_body(A, Wt, bias, outp, M, K, N, flags,
              blockIdx.x * 16, blockIdx.y * 128);
}

// fused QKV: z selects weight/output; V (z==2) written transposed [C][L]
__global__ __launch_bounds__(256) void mfma_gemm3(
        const short* __restrict__ A,
        const short* __restrict__ W0, const short* __restrict__ W1,
        const short* __restrict__ W2,
        short* __restrict__ o0, short* __restrict__ o1, short* __restrict__ o2,
        int M, int K, int N) {
    const short* Wt = (blockIdx.z == 0) ? W0 : (blockIdx.z == 1) ? W1 : W2;
    short* o = (blockIdx.z == 0) ? o0 : (blockIdx.z == 1) ? o1 : o2;
    int flags = (blockIdx.z == 2) ? 4 : 1;
    gemm_body(A, Wt, nullptr, o, M, K, N, flags, blockIdx.x * 16, 0);
}

// ---------------------------------------------------------------------------
// MFMA flash attention, fixed-shift softmax (exact: shift-invariant), split-K.
// One wave = 16 queries x 1 head x 1/KSPLIT of keys. V^T layout [C][L].
__global__ __launch_bounds__(64) void attn_mfma_kernel(
        const short* __restrict__ Qb, const short* __restrict__ Kb,
        const short* __restrict__ Vt, const float* __restrict__ kb,
        float* __restrict__ po, float* __restrict__ pl) {
    const int lane = threadIdx.x;
    const int lq = lane & 15;
    const int g  = lane >> 4;
    const int h  = blockIdx.y;
    const int q0 = blockIdx.x * 16;
    const int z  = blockIdx.z;
    const int hd0 = h * 16;

    const bf16x4 qf = *(const bf16x4*)(Qb + (size_t)(q0 + lq) * CC + hd0 + 4 * g);
    const short* kp = Kb + (size_t)lq * CC + hd0 + 4 * g;
    const short* vp = Vt + (size_t)(hd0 + lq) * LL + 4 * g;
    const float* bp = kb + 4 * g;

    f32x4 o = {0.f, 0.f, 0.f, 0.f};
    float psum = 0.f;

    for (int t = z; t < NTILE; t += KSPLIT) {
        const int k0 = t * 32;
        bf16x4 kf0 = *(const bf16x4*)(kp + (size_t)k0 * CC);
        bf16x4 kf1 = *(const bf16x4*)(kp + (size_t)(k0 + 16) * CC);
        bf16x4 vf0 = *(const bf16x4*)(vp + k0);
        bf16x4 vf1 = *(const bf16x4*)(vp + k0 + 16);
        f32x4 b0 = *(const f32x4*)(bp + k0);
        f32x4 b1 = *(const f32x4*)(bp + k0 + 16);

        const f32x4 zz = {0.f, 0.f, 0.f, 0.f};
        f32x4 s0 = __builtin_amdgcn_mfma_f32_16x16x16bf16_1k(kf0, qf, zz, 0, 0, 0);
        f32x4 s1 = __builtin_amdgcn_mfma_f32_16x16x16bf16_1k(kf1, qf, zz, 0, 0, 0);

        float p0[4], p1[4];
        #pragma unroll
        for (int r = 0; r < 4; ++r) {
            p0[r] = exp2f(fmaf(s0[r], SCLOG2, b0[r]));
            p1[r] = exp2f(fmaf(s1[r], SCLOG2, b1[r]));
            psum += p0[r] + p1[r];
        }
        bf16x4 pt0 = {bf16rne(p0[0]), bf16rne(p0[1]), bf16rne(p0[2]), bf16rne(p0[3])};
        bf16x4 pt1 = {bf16rne(p1[0]), bf16rne(p1[1]), bf16rne(p1[2]), bf16rne(p1[3])};

        o = __builtin_amdgcn_mfma_f32_16x16x16bf16_1k(vf0, pt0, o, 0, 0, 0);
        o = __builtin_amdgcn_mfma_f32_16x16x16bf16_1k(vf1, pt1, o, 0, 0, 0);
    }

    // partial O and partial l-sum (exact combine later; no max alignment needed)
    *(f32x4*)(po + (size_t)z * LL * CC + (size_t)(q0 + lq) * CC + hd0 + 4 * g) = o;
    psum += __shfl_xor(psum, 16);
    psum += __shfl_xor(psum, 32);
    if (g == 0) pl[(z * 8 + h) * LL + q0 + lq] = psum;
}

// combine: attb[q][c] = bf16( sum_z po / sum_z pl )
__global__ void attn_combine(const float* __restrict__ po,
                             const float* __restrict__ pl,
                             short* __restrict__ attb) {
    int i = blockIdx.x * blockDim.x + threadIdx.x;   // over L*C/4
    if (i >= LL * CC / 4) return;
    int q  = i >> 5;
    int c0 = (i & 31) * 4;
    int h  = c0 >> 4;
    size_t off = (size_t)q * CC + c0;
    f32x4 o = {0.f, 0.f, 0.f, 0.f};
    float l = 0.f;
    #pragma unroll
    for (int zz = 0; zz < KSPLIT; ++zz) {
        f32x4 t = *(const f32x4*)(po + (size_t)zz * LL * CC + off);
        o[0] += t[0]; o[1] += t[1]; o[2] += t[2]; o[3] += t[3];
        l += pl[(zz * 8 + h) * LL + q];
    }
    float inv = 1.f / l;
    bf16x4 res = {bf16rne(o[0] * inv), bf16rne(o[1] * inv),
                  bf16rne(o[2] * inv), bf16rne(o[3] * inv)};
    *(bf16x4*)(attb + off) = res;
}

// ---------------------------------------------------------------------------
// Fused residual-add + LayerNorm over C=128; writes f32 + bf16 copies.
__global__ void ln_kernel(const float* __restrict__ X,
                          const float* __restrict__ R,
                          const float* __restrict__ g,
                          const float* __restrict__ b,
                          float* __restrict__ out,
                          short* __restrict__ outb) {
    int row  = blockIdx.x;
    int lane = threadIdx.x;
    size_t off = (size_t)row * CC;
    float x0 = X[off + lane]      + R[off + lane];
    float x1 = X[off + 64 + lane] + R[off + 64 + lane];
    float s  = x0 + x1;
    float s2 = x0 * x0 + x1 * x1;
    #pragma unroll
    for (int w = 32; w >= 1; w >>= 1) {
        s  += __shfl_xor(s,  w);
        s2 += __shfl_xor(s2, w);
    }
    float mu   = s * (1.f / CC);
    float var  = s2 * (1.f / CC) - mu * mu;
    float rstd = rsqrtf(var + 1e-5f);
    float y0 = (x0 - mu) * rstd * g[lane]      + b[lane];
    float y1 = (x1 - mu) * rstd * g[lane + 64] + b[lane + 64];
    out[off + lane]      = y0;
    out[off + 64 + lane] = y1;
    outb[off + lane]      = bf16rne(y0);
    outb[off + 64 + lane] = bf16rne(y1);
}

// ---------------------------------------------------------------------------
extern "C" void kernel_launch(void* const* d_in, const int* in_sizes, int n_in,
                              void* d_out, int out_size, void* d_ws, size_t ws_size,
                              hipStream_t stream) {
    const float* z    = (const float*)d_in[0];
    const float* r    = (const float*)d_in[1];
    const float* se   = (const float*)d_in[2];
    const float* Wq   = (const float*)d_in[3];
    const float* Wk   = (const float*)d_in[4];
    const float* Wv   = (const float*)d_in[5];
    const float* Wp   = (const float*)d_in[6];
    const float* beta = (const float*)d_in[7];
    const float* ln1g = (const float*)d_in[8];
    const float* ln1b = (const float*)d_in[9];
    const float* w1   = (const float*)d_in[10];
    const float* b1   = (const float*)d_in[11];
    const float* w2   = (const float*)d_in[12];
    const float* b2   = (const float*)d_in[13];
    const float* ln2g = (const float*)d_in[14];
    const float* ln2b = (const float*)d_in[15];
    float* out = (float*)d_out;

    float* ws    = (float*)d_ws;
    float* tok   = ws;                               // 512000 f
    float* prj   = tok + LL * CC;                    // 512000 f
    float* kbias = prj + LL * CC;                    // 8000 f
    float* pl    = kbias + NLAYER * LL;              // KSPLIT*8*LL = 128000 f
    float* po    = pl + KSPLIT * 8 * LL;             // KSPLIT*LL*CC f = 8 MB
    short* hdn   = (short*)po;                       // aliased: FFN phase only
    short* tokb  = (short*)(po + (size_t)KSPLIT * LL * CC);
    short* attb  = tokb + LL * CC;
    short* Qb    = attb + LL * CC;
    short* Kb    = Qb   + LL * CC;
    short* Vt    = Kb   + LL * CC;                   // transposed [C][L]
    short* wt8   = Vt   + LL * CC;
    short* w1t   = wt8  + 8 * 16384;
    short* w2t   = w1t  + 65536;                     // total ~18 MB

    prep_weights<<<1024, 256, 0, stream>>>(Wq, Wk, Wv, Wp, w1, w2, wt8, w1t, w2t);
    tokenize_kernel<<<2000, 256, 0, stream>>>(z, se, tok, tokb);
    kbias_kernel<<<32, 256, 0, stream>>>(r, beta, kbias);

    for (int l = 0; l < NLAYER; ++l) {
        const short* wqt = wt8 + (size_t)(0 * 2 + l) * 16384;
        const short* wkt = wt8 + (size_t)(1 * 2 + l) * 16384;
        const short* wvt = wt8 + (size_t)(2 * 2 + l) * 16384;
        const short* wpt = wt8 + (size_t)(3 * 2 + l) * 16384;
        mfma_gemm3<<<dim3(LL / 16, 1, 3), 256, 0, stream>>>(
            tokb, wqt, wkt, wvt, Qb, Kb, Vt, LL, CC, CC);
        attn_mfma_kernel<<<dim3(LL / 16, 8, KSPLIT), 64, 0, stream>>>(
            Qb, Kb, Vt, kbias + l * LL, po, pl);
        attn_combine<<<(LL * CC / 4 + 255) / 256, 256, 0, stream>>>(po, pl, attb);
        mfma_gemm<<<dim3(LL / 16, 1), 256, 0, stream>>>(
            attb, wpt, nullptr, prj, LL, CC, CC, 0);
        ln_kernel<<<LL, 64, 0, stream>>>(prj, tok, ln1g + l * CC, ln1b + l * CC,
                                         tok, tokb);
    }

    mfma_gemm<<<dim3(LL / 16, 4), 256, 0, stream>>>(tokb, w1t, b1, hdn, LL, CC, 4 * CC, 1 | 2);
    mfma_gemm<<<dim3(LL / 16, 1), 256, 0, stream>>>(hdn, w2t, b2, prj, LL, 4 * CC, CC, 0);
    ln_kernel<<<LL, 64, 0, stream>>>(prj, tok, ln2g, ln2b, tok, tokb);

    detok_kernel<<<2000, 256, 0, stream>>>(tok, out);
}

// Round 5
// 245.083 us; speedup vs baseline: 1.1052x; 1.1052x over previous
//
#include <hip/hip_runtime.h>
#include <hip/hip_bf16.h>
#include <math.h>

// Problem constants: S=4, B=1, C=128, h=w=d=10 -> N=1000, L=4000, nL=2, H=8, Dh=16
#define LL 4000
#define CC 128
#define NN 1000
#define NLAYER 2
#define KSPLIT 4                        // == S; split-K aligned to sequences
#define SCLOG2 0.36067376022224085f    // 0.25 * log2(e)

typedef __attribute__((ext_vector_type(4))) short bf16x4;
typedef __attribute__((ext_vector_type(8))) short short8;
typedef __attribute__((ext_vector_type(4))) float f32x4;

__device__ __forceinline__ short bf16rne(float f) {
    return __builtin_bit_cast(short, __float2bfloat16(f));
}

// ---------------------------------------------------------------------------
// tokenize: z[S,1,C,N] + seq_embed[S,C] -> tok[L,C] (f32) + tokb (bf16)
__global__ void tokenize_kernel(const float* __restrict__ z,
                                const float* __restrict__ se,
                                float* __restrict__ tok,
                                short* __restrict__ tokb) {
    int idx = blockIdx.x * blockDim.x + threadIdx.x;
    if (idx >= LL * CC) return;
    int c = idx & (CC - 1);
    int t = idx >> 7;
    int s = t / NN;
    int n = t - s * NN;
    float v = z[(s * CC + c) * NN + n] + se[s * CC + c];
    tok[idx] = v;
    tokb[idx] = bf16rne(v);
}

// detokenize: tok[L,C] -> out[(s*C+c)*N + n]
__global__ void detok_kernel(const float* __restrict__ tok,
                             float* __restrict__ out) {
    int idx = blockIdx.x * blockDim.x + threadIdx.x;
    if (idx >= LL * CC) return;
    int n = idx % NN;
    int sc = idx / NN;
    int c = sc & (CC - 1);
    int s = sc >> 7;
    out[idx] = tok[(s * NN + n) * CC + c];
}

// kbw[l*KSPLIT+z] = r[z]^beta[l]  (per-sequence softmax weight; row term of
// log R is softmax-invariant, clamp inactive since r>=0.1)
__global__ void kbw_kernel(const float* __restrict__ r,
                           const float* __restrict__ beta,
                           float* __restrict__ kbw) {
    int idx = threadIdx.x;
    if (idx >= NLAYER * KSPLIT) return;
    int l = idx / KSPLIT;
    int z = idx - l * KSPLIT;
    kbw[idx] = exp2f(beta[l] * __log2f(r[z]));
}

// ---------------------------------------------------------------------------
// weight prep: bf16 + transpose -> Wt[N][K]
__global__ void prep_weights(const float* __restrict__ Wq, const float* __restrict__ Wk,
                             const float* __restrict__ Wv, const float* __restrict__ Wp,
                             const float* __restrict__ w1, const float* __restrict__ w2,
                             short* __restrict__ wt8, short* __restrict__ w1t,
                             short* __restrict__ w2t) {
    int idx = blockIdx.x * blockDim.x + threadIdx.x;
    if (idx < 8 * 16384) {
        int m = idx >> 14, i = idx & 16383;
        int n = i >> 7, k = i & 127;
        const float* src = (m < 2) ? Wq + (size_t)m * 16384
                         : (m < 4) ? Wk + (size_t)(m - 2) * 16384
                         : (m < 6) ? Wv + (size_t)(m - 4) * 16384
                                   : Wp + (size_t)(m - 6) * 16384;
        wt8[idx] = bf16rne(src[k * 128 + n]);
    } else if (idx < 8 * 16384 + 65536) {
        int i = idx - 8 * 16384;
        int n = i >> 7, k = i & 127;
        w1t[i] = bf16rne(w1[(size_t)k * 512 + n]);
    } else if (idx < 8 * 16384 + 2 * 65536) {
        int i = idx - 8 * 16384 - 65536;
        int n = i >> 9, k = i & 511;
        w2t[i] = bf16rne(w2[(size_t)k * 128 + n]);
    }
}

// ---------------------------------------------------------------------------
// MFMA GEMM body: out[M,N] = act(A[M,K] @ Wt[N,K]^T + bias)
// flags: 1 = bf16 out, 2 = exact GELU, 4 = bf16 TRANSPOSED out (out[N][M])
__device__ __forceinline__ void gemm_body(
        const short* __restrict__ A, const short* __restrict__ Wt,
        const float* __restrict__ bias, void* __restrict__ outp,
        int M, int K, int N, int flags, int row0, int col0) {
    __shared__ short Al[16][136];
    __shared__ short Wl[128][136];
    const int tid = threadIdx.x;
    const int lane = tid & 63;
    const int w = tid >> 6;
    const int lq = lane & 15, g = lane >> 4;

    f32x4 acc[2] = {{0.f,0.f,0.f,0.f},{0.f,0.f,0.f,0.f}};

    for (int kc = 0; kc < K; kc += 128) {
        {
            int r = tid >> 4, c = (tid & 15) * 8;
            *(short8*)&Al[r][c] = *(const short8*)(A + (size_t)(row0 + r) * K + kc + c);
        }
        {
            int c = (tid & 15) * 8;
            int nb = tid >> 4;
            #pragma unroll
            for (int i = 0; i < 8; ++i) {
                int n = nb + i * 16;
                *(short8*)&Wl[n][c] = *(const short8*)(Wt + (size_t)(col0 + n) * K + kc + c);
            }
        }
        __syncthreads();
        bf16x4 af[8];
        #pragma unroll
        for (int ks = 0; ks < 8; ++ks)
            af[ks] = *(const bf16x4*)&Al[lq][ks * 16 + g * 4];
        #pragma unroll
        for (int ct = 0; ct < 2; ++ct) {
            int n = (w * 2 + ct) * 16 + lq;
            #pragma unroll
            for (int ks = 0; ks < 8; ++ks) {
                bf16x4 bfr = *(const bf16x4*)&Wl[n][ks * 16 + g * 4];
                acc[ct] = __builtin_amdgcn_mfma_f32_16x16x16bf16_1k(af[ks], bfr, acc[ct], 0, 0, 0);
            }
        }
        __syncthreads();
    }
    #pragma unroll
    for (int ct = 0; ct < 2; ++ct) {
        int col = col0 + (w * 2 + ct) * 16 + lq;
        float bv = bias ? bias[col] : 0.f;
        float v[4];
        #pragma unroll
        for (int r = 0; r < 4; ++r) {
            v[r] = acc[ct][r] + bv;
            if (flags & 2) v[r] = 0.5f * v[r] * (1.f + erff(v[r] * 0.70710678118654752f));
        }
        if (flags & 4) {
            bf16x4 res = {bf16rne(v[0]), bf16rne(v[1]), bf16rne(v[2]), bf16rne(v[3])};
            *(bf16x4*)((short*)outp + (size_t)col * M + row0 + g * 4) = res;
        } else if (flags & 1) {
            #pragma unroll
            for (int r = 0; r < 4; ++r)
                ((short*)outp)[(size_t)(row0 + g * 4 + r) * N + col] = bf16rne(v[r]);
        } else {
            #pragma unroll
            for (int r = 0; r < 4; ++r)
                ((float*)outp)[(size_t)(row0 + g * 4 + r) * N + col] = v[r];
        }
    }
}

__global__ __launch_bounds__(256) void mfma_gemm(
        const short* __restrict__ A, const short* __restrict__ Wt,
        const float* __restrict__ bias, void* __restrict__ outp,
        int M, int K, int N, int flags) {
    gemm_body(A, Wt, bias, outp, M, K, N, flags,
              blockIdx.x * 16, blockIdx.y * 128);
}

// fused QKV: z selects weight/output; V (z==2) written transposed [C][L]
__global__ __launch_bounds__(256) void mfma_gemm3(
        const short* __restrict__ A,
        const short* __restrict__ W0, const short* __restrict__ W1,
        const short* __restrict__ W2,
        short* __restrict__ o0, short* __restrict__ o1, short* __restrict__ o2,
        int M, int K, int N) {
    const short* Wt = (blockIdx.z == 0) ? W0 : (blockIdx.z == 1) ? W1 : W2;
    short* o = (blockIdx.z == 0) ? o0 : (blockIdx.z == 1) ? o1 : o2;
    int flags = (blockIdx.z == 2) ? 4 : 1;
    gemm_body(A, Wt, nullptr, o, M, K, N, flags, blockIdx.x * 16, 0);
}

// ---------------------------------------------------------------------------
// MFMA flash attention, fixed-shift softmax, sequence-aligned split-K.
// Wave = 16 queries x 1 head x sequence z (keys z*1000..z*1000+999).
// Bias reduces to scalar w_z = r_z^beta applied in epilogue. Depth-2
// register pipeline: named buffers A/B, prefetch i+2/i+3 before computing.
__global__ __launch_bounds__(64) void attn_mfma_kernel(
        const short* __restrict__ Qb, const short* __restrict__ Kb,
        const short* __restrict__ Vt, const float* __restrict__ kbw,
        float* __restrict__ po, float* __restrict__ pl) {
    const int lane = threadIdx.x;
    const int lq = lane & 15;
    const int g  = lane >> 4;
    const int h  = blockIdx.y;
    const int q0 = blockIdx.x * 16;
    const int z  = blockIdx.z;
    const int hd0 = h * 16;
    const int kbase = z * NN;

    const bf16x4 qf = *(const bf16x4*)(Qb + (size_t)(q0 + lq) * CC + hd0 + 4 * g);
    const short* kp = Kb + (size_t)lq * CC + hd0 + 4 * g;      // + key*CC
    const short* vp = Vt + (size_t)(hd0 + lq) * LL + 4 * g;    // + key

    f32x4 o = {0.f, 0.f, 0.f, 0.f};
    float psum = 0.f;

    // 31 full 32-key tiles (keys 0..991 local) + 8-key tail (992..999)
    #define LOADT(i, K0, K1, V0, V1)                                          \
        {   int k0_ = kbase + (i) * 32;                                       \
            K0 = *(const bf16x4*)(kp + (size_t)k0_ * CC);                     \
            K1 = *(const bf16x4*)(kp + (size_t)(k0_ + 16) * CC);              \
            V0 = *(const bf16x4*)(vp + k0_);                                  \
            V1 = *(const bf16x4*)(vp + k0_ + 16); }

    #define COMPUTET(K0, K1, V0, V1)                                          \
        {   const f32x4 zz_ = {0.f, 0.f, 0.f, 0.f};                           \
            f32x4 s0_ = __builtin_amdgcn_mfma_f32_16x16x16bf16_1k(K0, qf, zz_, 0, 0, 0); \
            f32x4 s1_ = __builtin_amdgcn_mfma_f32_16x16x16bf16_1k(K1, qf, zz_, 0, 0, 0); \
            float p0_[4], p1_[4];                                             \
            _Pragma("unroll")                                                 \
            for (int r_ = 0; r_ < 4; ++r_) {                                  \
                p0_[r_] = exp2f(s0_[r_] * SCLOG2);                            \
                p1_[r_] = exp2f(s1_[r_] * SCLOG2);                            \
                psum += p0_[r_] + p1_[r_];                                    \
            }                                                                 \
            bf16x4 pt0_ = {bf16rne(p0_[0]), bf16rne(p0_[1]), bf16rne(p0_[2]), bf16rne(p0_[3])}; \
            bf16x4 pt1_ = {bf16rne(p1_[0]), bf16rne(p1_[1]), bf16rne(p1_[2]), bf16rne(p1_[3])}; \
            o = __builtin_amdgcn_mfma_f32_16x16x16bf16_1k(V0, pt0_, o, 0, 0, 0); \
            o = __builtin_amdgcn_mfma_f32_16x16x16bf16_1k(V1, pt1_, o, 0, 0, 0); }

    bf16x4 kA0, kA1, vA0, vA1, kB0, kB1, vB0, vB1, kN0, kN1, vN0, vN1;
    LOADT(0, kA0, kA1, vA0, vA1);
    LOADT(1, kB0, kB1, vB0, vB1);

    for (int i = 0; i < 30; i += 2) {
        LOADT(i + 2, kN0, kN1, vN0, vN1);                // tiles 2..30 (real)
        COMPUTET(kA0, kA1, vA0, vA1);
        kA0 = kN0; kA1 = kN1; vA0 = vN0; vA1 = vN1;
        int i3 = (i + 3 <= 30) ? i + 3 : 0;              // dummy on last iter
        LOADT(i3, kN0, kN1, vN0, vN1);
        COMPUTET(kB0, kB1, vB0, vB1);
        kB0 = kN0; kB1 = kN1; vB0 = vN0; vB1 = vN1;
    }
    COMPUTET(kA0, kA1, vA0, vA1);                        // tile 30

    {   // tail: 8 keys (992..999 local) via one 16-key MFMA, lane-uniform mask
        int k0 = kbase + 992;
        bf16x4 kf = *(const bf16x4*)(kp + (size_t)k0 * CC);
        bf16x4 vf = *(const bf16x4*)(vp + k0);
        const f32x4 zz = {0.f, 0.f, 0.f, 0.f};
        f32x4 s0 = __builtin_amdgcn_mfma_f32_16x16x16bf16_1k(kf, qf, zz, 0, 0, 0);
        float mask = (g < 2) ? 1.f : 0.f;                // keys 4g+r < 8
        float p0[4];
        #pragma unroll
        for (int r = 0; r < 4; ++r) {
            p0[r] = exp2f(s0[r] * SCLOG2) * mask;
            psum += p0[r];
        }
        bf16x4 pt0 = {bf16rne(p0[0]), bf16rne(p0[1]), bf16rne(p0[2]), bf16rne(p0[3])};
        o = __builtin_amdgcn_mfma_f32_16x16x16bf16_1k(vf, pt0, o, 0, 0, 0);
    }

    const float wz = kbw[z];
    psum += __shfl_xor(psum, 16);
    psum += __shfl_xor(psum, 32);
    f32x4 ow = {o[0] * wz, o[1] * wz, o[2] * wz, o[3] * wz};
    *(f32x4*)(po + (size_t)z * LL * CC + (size_t)(q0 + lq) * CC + hd0 + 4 * g) = ow;
    if (g == 0) pl[(z * 8 + h) * LL + q0 + lq] = psum * wz;
    #undef LOADT
    #undef COMPUTET
}

// combine: attb[q][c] = bf16( sum_z po / sum_z pl )
__global__ void attn_combine(const float* __restrict__ po,
                             const float* __restrict__ pl,
                             short* __restrict__ attb) {
    int i = blockIdx.x * blockDim.x + threadIdx.x;
    if (i >= LL * CC / 4) return;
    int q  = i >> 5;
    int c0 = (i & 31) * 4;
    int h  = c0 >> 4;
    size_t off = (size_t)q * CC + c0;
    f32x4 o = {0.f, 0.f, 0.f, 0.f};
    float l = 0.f;
    #pragma unroll
    for (int zz = 0; zz < KSPLIT; ++zz) {
        f32x4 t = *(const f32x4*)(po + (size_t)zz * LL * CC + off);
        o[0] += t[0]; o[1] += t[1]; o[2] += t[2]; o[3] += t[3];
        l += pl[(zz * 8 + h) * LL + q];
    }
    float inv = 1.f / l;
    bf16x4 res = {bf16rne(o[0] * inv), bf16rne(o[1] * inv),
                  bf16rne(o[2] * inv), bf16rne(o[3] * inv)};
    *(bf16x4*)(attb + off) = res;
}

// ---------------------------------------------------------------------------
// Fused residual-add + LayerNorm over C=128; writes f32 + bf16 copies.
__global__ void ln_kernel(const float* __restrict__ X,
                          const float* __restrict__ R,
                          const float* __restrict__ g,
                          const float* __restrict__ b,
                          float* __restrict__ out,
                          short* __restrict__ outb) {
    int row  = blockIdx.x;
    int lane = threadIdx.x;
    size_t off = (size_t)row * CC;
    float x0 = X[off + lane]      + R[off + lane];
    float x1 = X[off + 64 + lane] + R[off + 64 + lane];
    float s  = x0 + x1;
    float s2 = x0 * x0 + x1 * x1;
    #pragma unroll
    for (int w = 32; w >= 1; w >>= 1) {
        s  += __shfl_xor(s,  w);
        s2 += __shfl_xor(s2, w);
    }
    float mu   = s * (1.f / CC);
    float var  = s2 * (1.f / CC) - mu * mu;
    float rstd = rsqrtf(var + 1e-5f);
    float y0 = (x0 - mu) * rstd * g[lane]      + b[lane];
    float y1 = (x1 - mu) * rstd * g[lane + 64] + b[lane + 64];
    out[off + lane]      = y0;
    out[off + 64 + lane] = y1;
    outb[off + lane]      = bf16rne(y0);
    outb[off + 64 + lane] = bf16rne(y1);
}

// ---------------------------------------------------------------------------
extern "C" void kernel_launch(void* const* d_in, const int* in_sizes, int n_in,
                              void* d_out, int out_size, void* d_ws, size_t ws_size,
                              hipStream_t stream) {
    const float* z    = (const float*)d_in[0];
    const float* r    = (const float*)d_in[1];
    const float* se   = (const float*)d_in[2];
    const float* Wq   = (const float*)d_in[3];
    const float* Wk   = (const float*)d_in[4];
    const float* Wv   = (const float*)d_in[5];
    const float* Wp   = (const float*)d_in[6];
    const float* beta = (const float*)d_in[7];
    const float* ln1g = (const float*)d_in[8];
    const float* ln1b = (const float*)d_in[9];
    const float* w1   = (const float*)d_in[10];
    const float* b1   = (const float*)d_in[11];
    const float* w2   = (const float*)d_in[12];
    const float* b2   = (const float*)d_in[13];
    const float* ln2g = (const float*)d_in[14];
    const float* ln2b = (const float*)d_in[15];
    float* out = (float*)d_out;

    float* ws    = (float*)d_ws;
    float* tok   = ws;                               // 512000 f
    float* prj   = tok + LL * CC;                    // 512000 f
    float* kbw   = prj + LL * CC;                    // 8 f
    float* pl    = kbw + 8;                          // KSPLIT*8*LL f
    float* po    = pl + KSPLIT * 8 * LL;             // KSPLIT*LL*CC f = 8 MB
    short* hdn   = (short*)po;                       // aliased: FFN phase only
    short* tokb  = (short*)(po + (size_t)KSPLIT * LL * CC);
    short* attb  = tokb + LL * CC;
    short* Qb    = attb + LL * CC;
    short* Kb    = Qb   + LL * CC;
    short* Vt    = Kb   + LL * CC;                   // transposed [C][L]
    short* wt8   = Vt   + LL * CC;
    short* w1t   = wt8  + 8 * 16384;
    short* w2t   = w1t  + 65536;

    prep_weights<<<1024, 256, 0, stream>>>(Wq, Wk, Wv, Wp, w1, w2, wt8, w1t, w2t);
    tokenize_kernel<<<2000, 256, 0, stream>>>(z, se, tok, tokb);
    kbw_kernel<<<1, 64, 0, stream>>>(r, beta, kbw);

    for (int l = 0; l < NLAYER; ++l) {
        const short* wqt = wt8 + (size_t)(0 * 2 + l) * 16384;
        const short* wkt = wt8 + (size_t)(1 * 2 + l) * 16384;
        const short* wvt = wt8 + (size_t)(2 * 2 + l) * 16384;
        const short* wpt = wt8 + (size_t)(3 * 2 + l) * 16384;
        mfma_gemm3<<<dim3(LL / 16, 1, 3), 256, 0, stream>>>(
            tokb, wqt, wkt, wvt, Qb, Kb, Vt, LL, CC, CC);
        attn_mfma_kernel<<<dim3(LL / 16, 8, KSPLIT), 64, 0, stream>>>(
            Qb, Kb, Vt, kbw + l * KSPLIT, po, pl);
        attn_combine<<<(LL * CC / 4 + 255) / 256, 256, 0, stream>>>(po, pl, attb);
        mfma_gemm<<<dim3(LL / 16, 1), 256, 0, stream>>>(
            attb, wpt, nullptr, prj, LL, CC, CC, 0);
        ln_kernel<<<LL, 64, 0, stream>>>(prj, tok, ln1g + l * CC, ln1b + l * CC,
                                         tok, tokb);
    }

    mfma_gemm<<<dim3(LL / 16, 4), 256, 0, stream>>>(tokb, w1t, b1, hdn, LL, CC, 4 * CC, 1 | 2);
    mfma_gemm<<<dim3(LL / 16, 1), 256, 0, stream>>>(hdn, w2t, b2, prj, LL, 4 * CC, CC, 0);
    ln_kernel<<<LL, 64, 0, stream>>>(prj, tok, ln2g, ln2b, tok, tokb);

    detok_kernel<<<2000, 256, 0, stream>>>(tok, out);
}

// Round 6
// 243.299 us; speedup vs baseline: 1.1133x; 1.0073x over previous
//
#include <hip/hip_runtime.h>
#include <hip/hip_bf16.h>
#include <math.h>

// Problem constants: S=4, B=1, C=128, h=w=d=10 -> N=1000, L=4000, nL=2, H=8, Dh=16
#define LL 4000
#define CC 128
#define NN 1000
#define NLAYER 2
#define KSPLIT 4                        // == S; split-K aligned to sequences
#define SCLOG2 0.36067376022224085f    // 0.25 * log2(e), folded into Q

typedef __attribute__((ext_vector_type(4))) short bf16x4;
typedef __attribute__((ext_vector_type(8))) short short8;
typedef __attribute__((ext_vector_type(4))) float f32x4;
typedef __attribute__((ext_vector_type(2))) unsigned int u32x2;

__device__ __forceinline__ short bf16rne(float f) {
    return __builtin_bit_cast(short, __float2bfloat16(f));
}

// pack 4 f32 -> 4 bf16 (truncate) via 2x v_perm_b32
__device__ __forceinline__ bf16x4 pack4(const float* p) {
    unsigned w01 = __builtin_amdgcn_perm(__builtin_bit_cast(unsigned, p[1]),
                                         __builtin_bit_cast(unsigned, p[0]),
                                         0x07060302u);
    unsigned w23 = __builtin_amdgcn_perm(__builtin_bit_cast(unsigned, p[3]),
                                         __builtin_bit_cast(unsigned, p[2]),
                                         0x07060302u);
    u32x2 w = {w01, w23};
    return __builtin_bit_cast(bf16x4, w);
}

// ---------------------------------------------------------------------------
// tokenize: z[S,1,C,N] + seq_embed[S,C] -> tok[L,C] (f32) + tokb (bf16)
__global__ void tokenize_kernel(const float* __restrict__ z,
                                const float* __restrict__ se,
                                float* __restrict__ tok,
                                short* __restrict__ tokb) {
    int idx = blockIdx.x * blockDim.x + threadIdx.x;
    if (idx >= LL * CC) return;
    int c = idx & (CC - 1);
    int t = idx >> 7;
    int s = t / NN;
    int n = t - s * NN;
    float v = z[(s * CC + c) * NN + n] + se[s * CC + c];
    tok[idx] = v;
    tokb[idx] = bf16rne(v);
}

// detokenize: tok[L,C] -> out[(s*C+c)*N + n]
__global__ void detok_kernel(const float* __restrict__ tok,
                             float* __restrict__ out) {
    int idx = blockIdx.x * blockDim.x + threadIdx.x;
    if (idx >= LL * CC) return;
    int n = idx % NN;
    int sc = idx / NN;
    int c = sc & (CC - 1);
    int s = sc >> 7;
    out[idx] = tok[(s * NN + n) * CC + c];
}

// kbw[l*KSPLIT+z] = r[z]^beta[l]  (per-sequence softmax weight; row term of
// log R is softmax-invariant, clamp inactive since r>=0.1)
__global__ void kbw_kernel(const float* __restrict__ r,
                           const float* __restrict__ beta,
                           float* __restrict__ kbw) {
    int idx = threadIdx.x;
    if (idx >= NLAYER * KSPLIT) return;
    int l = idx / KSPLIT;
    int z = idx - l * KSPLIT;
    kbw[idx] = exp2f(beta[l] * __log2f(r[z]));
}

// ---------------------------------------------------------------------------
// weight prep: bf16 + transpose -> Wt[N][K]
__global__ void prep_weights(const float* __restrict__ Wq, const float* __restrict__ Wk,
                             const float* __restrict__ Wv, const float* __restrict__ Wp,
                             const float* __restrict__ w1, const float* __restrict__ w2,
                             short* __restrict__ wt8, short* __restrict__ w1t,
                             short* __restrict__ w2t) {
    int idx = blockIdx.x * blockDim.x + threadIdx.x;
    if (idx < 8 * 16384) {
        int m = idx >> 14, i = idx & 16383;
        int n = i >> 7, k = i & 127;
        const float* src = (m < 2) ? Wq + (size_t)m * 16384
                         : (m < 4) ? Wk + (size_t)(m - 2) * 16384
                         : (m < 6) ? Wv + (size_t)(m - 4) * 16384
                                   : Wp + (size_t)(m - 6) * 16384;
        wt8[idx] = bf16rne(src[k * 128 + n]);
    } else if (idx < 8 * 16384 + 65536) {
        int i = idx - 8 * 16384;
        int n = i >> 7, k = i & 127;
        w1t[i] = bf16rne(w1[(size_t)k * 512 + n]);
    } else if (idx < 8 * 16384 + 2 * 65536) {
        int i = idx - 8 * 16384 - 65536;
        int n = i >> 9, k = i & 511;
        w2t[i] = bf16rne(w2[(size_t)k * 128 + n]);
    }
}

// ---------------------------------------------------------------------------
// MFMA GEMM body: out[M,N] = act(A[M,K] @ Wt[N,K]^T + bias)
// flags: 1 = bf16 out, 2 = exact GELU, 4 = bf16 transposed out, 8 = *SCLOG2
__device__ __forceinline__ void gemm_body(
        const short* __restrict__ A, const short* __restrict__ Wt,
        const float* __restrict__ bias, void* __restrict__ outp,
        int M, int K, int N, int flags, int row0, int col0) {
    __shared__ short Al[16][136];
    __shared__ short Wl[128][136];
    const int tid = threadIdx.x;
    const int lane = tid & 63;
    const int w = tid >> 6;
    const int lq = lane & 15, g = lane >> 4;

    f32x4 acc[2] = {{0.f,0.f,0.f,0.f},{0.f,0.f,0.f,0.f}};

    for (int kc = 0; kc < K; kc += 128) {
        {
            int r = tid >> 4, c = (tid & 15) * 8;
            *(short8*)&Al[r][c] = *(const short8*)(A + (size_t)(row0 + r) * K + kc + c);
        }
        {
            int c = (tid & 15) * 8;
            int nb = tid >> 4;
            #pragma unroll
            for (int i = 0; i < 8; ++i) {
                int n = nb + i * 16;
                *(short8*)&Wl[n][c] = *(const short8*)(Wt + (size_t)(col0 + n) * K + kc + c);
            }
        }
        __syncthreads();
        bf16x4 af[8];
        #pragma unroll
        for (int ks = 0; ks < 8; ++ks)
            af[ks] = *(const bf16x4*)&Al[lq][ks * 16 + g * 4];
        #pragma unroll
        for (int ct = 0; ct < 2; ++ct) {
            int n = (w * 2 + ct) * 16 + lq;
            #pragma unroll
            for (int ks = 0; ks < 8; ++ks) {
                bf16x4 bfr = *(const bf16x4*)&Wl[n][ks * 16 + g * 4];
                acc[ct] = __builtin_amdgcn_mfma_f32_16x16x16bf16_1k(af[ks], bfr, acc[ct], 0, 0, 0);
            }
        }
        __syncthreads();
    }
    #pragma unroll
    for (int ct = 0; ct < 2; ++ct) {
        int col = col0 + (w * 2 + ct) * 16 + lq;
        float bv = bias ? bias[col] : 0.f;
        float v[4];
        #pragma unroll
        for (int r = 0; r < 4; ++r) {
            v[r] = acc[ct][r] + bv;
            if (flags & 2) v[r] = 0.5f * v[r] * (1.f + erff(v[r] * 0.70710678118654752f));
            if (flags & 8) v[r] *= SCLOG2;
        }
        if (flags & 4) {
            bf16x4 res = {bf16rne(v[0]), bf16rne(v[1]), bf16rne(v[2]), bf16rne(v[3])};
            *(bf16x4*)((short*)outp + (size_t)col * M + row0 + g * 4) = res;
        } else if (flags & 1) {
            #pragma unroll
            for (int r = 0; r < 4; ++r)
                ((short*)outp)[(size_t)(row0 + g * 4 + r) * N + col] = bf16rne(v[r]);
        } else {
            #pragma unroll
            for (int r = 0; r < 4; ++r)
                ((float*)outp)[(size_t)(row0 + g * 4 + r) * N + col] = v[r];
        }
    }
}

__global__ __launch_bounds__(256) void mfma_gemm(
        const short* __restrict__ A, const short* __restrict__ Wt,
        const float* __restrict__ bias, void* __restrict__ outp,
        int M, int K, int N, int flags) {
    gemm_body(A, Wt, bias, outp, M, K, N, flags,
              blockIdx.x * 16, blockIdx.y * 128);
}

// fused QKV: z selects weight/output; Q scaled by SCLOG2; V transposed [C][L]
__global__ __launch_bounds__(256) void mfma_gemm3(
        const short* __restrict__ A,
        const short* __restrict__ W0, const short* __restrict__ W1,
        const short* __restrict__ W2,
        short* __restrict__ o0, short* __restrict__ o1, short* __restrict__ o2,
        int M, int K, int N) {
    const short* Wt = (blockIdx.z == 0) ? W0 : (blockIdx.z == 1) ? W1 : W2;
    short* o = (blockIdx.z == 0) ? o0 : (blockIdx.z == 1) ? o1 : o2;
    int flags = (blockIdx.z == 0) ? (1 | 8) : (blockIdx.z == 1) ? 1 : 4;
    gemm_body(A, Wt, nullptr, o, M, K, N, flags, blockIdx.x * 16, 0);
}

// ---------------------------------------------------------------------------
// MFMA flash attention, fixed-shift softmax, sequence-aligned split-K.
// 4 waves/block (occupancy: clears the 16-workgroup/CU cap of 1-wave blocks).
// Wave = 16 queries x 1 head x sequence z. Q pre-scaled by 0.25*log2e.
// P packed to bf16 by truncation (v_perm); Sum(p) accumulated via MFMA with a
// ones-row A fragment -> denominator uses the SAME truncated values (bias
// cancels in p/sum(p)).
__global__ __launch_bounds__(256) void attn_mfma_kernel(
        const short* __restrict__ Qb, const short* __restrict__ Kb,
        const short* __restrict__ Vt, const float* __restrict__ kbw,
        float* __restrict__ po, float* __restrict__ pl) {
    const int lane = threadIdx.x;
    const int lq = lane & 15;
    const int g  = lane >> 4;
    const int qt = blockIdx.x * 4 + threadIdx.y;
    if (qt >= LL / 16) return;           // wave-uniform exit (2 pad waves)
    const int h  = blockIdx.y;
    const int z  = blockIdx.z;
    const int q0 = qt * 16;
    const int hd0 = h * 16;
    const int kbase = z * NN;

    const bf16x4 qf = *(const bf16x4*)(Qb + (size_t)(q0 + lq) * CC + hd0 + 4 * g);
    const short* kp = Kb + (size_t)(kbase + lq) * CC + hd0 + 4 * g;  // + key*CC
    const short* vp = Vt + (size_t)(hd0 + lq) * LL + kbase + 4 * g;  // + key

    // ones-row A fragment: A[0][k] = 1 -> D[0][q] = sum_k P[k][q]
    const short onev = (lq == 0) ? (short)0x3F80 : (short)0;
    const bf16x4 af1 = {onev, onev, onev, onev};

    f32x4 o  = {0.f, 0.f, 0.f, 0.f};
    f32x4 ps = {0.f, 0.f, 0.f, 0.f};

    bf16x4 kb0[3], kb1[3], vb0[3], vb1[3];

    auto loadt = [&](int i, int b) {
        int k0 = i * 32;
        kb0[b] = *(const bf16x4*)(kp + (size_t)k0 * CC);
        kb1[b] = *(const bf16x4*)(kp + (size_t)(k0 + 16) * CC);
        vb0[b] = *(const bf16x4*)(vp + k0);
        vb1[b] = *(const bf16x4*)(vp + k0 + 16);
    };
    auto compute = [&](bf16x4 K0, bf16x4 K1, bf16x4 V0, bf16x4 V1) {
        const f32x4 zz = {0.f, 0.f, 0.f, 0.f};
        f32x4 s0 = __builtin_amdgcn_mfma_f32_16x16x16bf16_1k(K0, qf, zz, 0, 0, 0);
        f32x4 s1 = __builtin_amdgcn_mfma_f32_16x16x16bf16_1k(K1, qf, zz, 0, 0, 0);
        float p0[4], p1[4];
        #pragma unroll
        for (int r = 0; r < 4; ++r) {
            p0[r] = __builtin_amdgcn_exp2f(s0[r]);
            p1[r] = __builtin_amdgcn_exp2f(s1[r]);
        }
        bf16x4 pt0 = pack4(p0);
        bf16x4 pt1 = pack4(p1);
        o  = __builtin_amdgcn_mfma_f32_16x16x16bf16_1k(V0, pt0, o, 0, 0, 0);
        o  = __builtin_amdgcn_mfma_f32_16x16x16bf16_1k(V1, pt1, o, 0, 0, 0);
        ps = __builtin_amdgcn_mfma_f32_16x16x16bf16_1k(af1, pt0, ps, 0, 0, 0);
        ps = __builtin_amdgcn_mfma_f32_16x16x16bf16_1k(af1, pt1, ps, 0, 0, 0);
    };

    // 31 full 32-key tiles (keys 0..991 local), depth-3 register pipeline
    loadt(0, 0);
    loadt(1, 1);
    #pragma unroll
    for (int i = 0; i < 31; ++i) {
        if (i + 2 < 31) loadt(i + 2, (i + 2) % 3);
        const int b = i % 3;
        compute(kb0[b], kb1[b], vb0[b], vb1[b]);
    }

    {   // tail: 8 keys (992..999 local), one 16-key MFMA, select-mask pre-use
        bf16x4 kf = *(const bf16x4*)(kp + (size_t)992 * CC);
        bf16x4 vf = *(const bf16x4*)(vp + 992);
        const f32x4 zz = {0.f, 0.f, 0.f, 0.f};
        f32x4 s0 = __builtin_amdgcn_mfma_f32_16x16x16bf16_1k(kf, qf, zz, 0, 0, 0);
        float p0[4];
        #pragma unroll
        for (int r = 0; r < 4; ++r)
            p0[r] = (g < 2) ? __builtin_amdgcn_exp2f(s0[r]) : 0.f;  // keys >= 1000 masked
        bf16x4 pt0 = pack4(p0);
        o  = __builtin_amdgcn_mfma_f32_16x16x16bf16_1k(vf, pt0, o, 0, 0, 0);
        ps = __builtin_amdgcn_mfma_f32_16x16x16bf16_1k(af1, pt0, ps, 0, 0, 0);
    }

    const float wz = kbw[z];
    f32x4 ow = {o[0] * wz, o[1] * wz, o[2] * wz, o[3] * wz};
    *(f32x4*)(po + (size_t)z * LL * CC + (size_t)(q0 + lq) * CC + hd0 + 4 * g) = ow;
    if (g == 0) pl[(z * 8 + h) * LL + q0 + lq] = ps[0] * wz;
}

// combine: attb[q][c] = bf16( sum_z po / sum_z pl )
__global__ void attn_combine(const float* __restrict__ po,
                             const float* __restrict__ pl,
                             short* __restrict__ attb) {
    int i = blockIdx.x * blockDim.x + threadIdx.x;
    if (i >= LL * CC / 4) return;
    int q  = i >> 5;
    int c0 = (i & 31) * 4;
    int h  = c0 >> 4;
    size_t off = (size_t)q * CC + c0;
    f32x4 o = {0.f, 0.f, 0.f, 0.f};
    float l = 0.f;
    #pragma unroll
    for (int zz = 0; zz < KSPLIT; ++zz) {
        f32x4 t = *(const f32x4*)(po + (size_t)zz * LL * CC + off);
        o[0] += t[0]; o[1] += t[1]; o[2] += t[2]; o[3] += t[3];
        l += pl[(zz * 8 + h) * LL + q];
    }
    float inv = 1.f / l;
    bf16x4 res = {bf16rne(o[0] * inv), bf16rne(o[1] * inv),
                  bf16rne(o[2] * inv), bf16rne(o[3] * inv)};
    *(bf16x4*)(attb + off) = res;
}

// ---------------------------------------------------------------------------
// Fused residual-add + LayerNorm over C=128; writes f32 + bf16 copies.
__global__ void ln_kernel(const float* __restrict__ X,
                          const float* __restrict__ R,
                          const float* __restrict__ g,
                          const float* __restrict__ b,
                          float* __restrict__ out,
                          short* __restrict__ outb) {
    int row  = blockIdx.x;
    int lane = threadIdx.x;
    size_t off = (size_t)row * CC;
    float x0 = X[off + lane]      + R[off + lane];
    float x1 = X[off + 64 + lane] + R[off + 64 + lane];
    float s  = x0 + x1;
    float s2 = x0 * x0 + x1 * x1;
    #pragma unroll
    for (int w = 32; w >= 1; w >>= 1) {
        s  += __shfl_xor(s,  w);
        s2 += __shfl_xor(s2, w);
    }
    float mu   = s * (1.f / CC);
    float var  = s2 * (1.f / CC) - mu * mu;
    float rstd = rsqrtf(var + 1e-5f);
    float y0 = (x0 - mu) * rstd * g[lane]      + b[lane];
    float y1 = (x1 - mu) * rstd * g[lane + 64] + b[lane + 64];
    out[off + lane]      = y0;
    out[off + 64 + lane] = y1;
    outb[off + lane]      = bf16rne(y0);
    outb[off + 64 + lane] = bf16rne(y1);
}

// ---------------------------------------------------------------------------
extern "C" void kernel_launch(void* const* d_in, const int* in_sizes, int n_in,
                              void* d_out, int out_size, void* d_ws, size_t ws_size,
                              hipStream_t stream) {
    const float* z    = (const float*)d_in[0];
    const float* r    = (const float*)d_in[1];
    const float* se   = (const float*)d_in[2];
    const float* Wq   = (const float*)d_in[3];
    const float* Wk   = (const float*)d_in[4];
    const float* Wv   = (const float*)d_in[5];
    const float* Wp   = (const float*)d_in[6];
    const float* beta = (const float*)d_in[7];
    const float* ln1g = (const float*)d_in[8];
    const float* ln1b = (const float*)d_in[9];
    const float* w1   = (const float*)d_in[10];
    const float* b1   = (const float*)d_in[11];
    const float* w2   = (const float*)d_in[12];
    const float* b2   = (const float*)d_in[13];
    const float* ln2g = (const float*)d_in[14];
    const float* ln2b = (const float*)d_in[15];
    float* out = (float*)d_out;

    float* ws    = (float*)d_ws;
    float* tok   = ws;                               // 512000 f
    float* prj   = tok + LL * CC;                    // 512000 f
    float* kbw   = prj + LL * CC;                    // 8 f
    float* pl    = kbw + 8;                          // KSPLIT*8*LL f
    float* po    = pl + KSPLIT * 8 * LL;             // KSPLIT*LL*CC f = 8 MB
    short* hdn   = (short*)po;                       // aliased: FFN phase only
    short* tokb  = (short*)(po + (size_t)KSPLIT * LL * CC);
    short* attb  = tokb + LL * CC;
    short* Qb    = attb + LL * CC;
    short* Kb    = Qb   + LL * CC;
    short* Vt    = Kb   + LL * CC;                   // transposed [C][L]
    short* wt8   = Vt   + LL * CC;
    short* w1t   = wt8  + 8 * 16384;
    short* w2t   = w1t  + 65536;

    prep_weights<<<1024, 256, 0, stream>>>(Wq, Wk, Wv, Wp, w1, w2, wt8, w1t, w2t);
    tokenize_kernel<<<2000, 256, 0, stream>>>(z, se, tok, tokb);
    kbw_kernel<<<1, 64, 0, stream>>>(r, beta, kbw);

    for (int l = 0; l < NLAYER; ++l) {
        const short* wqt = wt8 + (size_t)(0 * 2 + l) * 16384;
        const short* wkt = wt8 + (size_t)(1 * 2 + l) * 16384;
        const short* wvt = wt8 + (size_t)(2 * 2 + l) * 16384;
        const short* wpt = wt8 + (size_t)(3 * 2 + l) * 16384;
        mfma_gemm3<<<dim3(LL / 16, 1, 3), 256, 0, stream>>>(
            tokb, wqt, wkt, wvt, Qb, Kb, Vt, LL, CC, CC);
        attn_mfma_kernel<<<dim3((LL / 16 + 3) / 4, 8, KSPLIT), dim3(64, 4), 0, stream>>>(
            Qb, Kb, Vt, kbw + l * KSPLIT, po, pl);
        attn_combine<<<(LL * CC / 4 + 255) / 256, 256, 0, stream>>>(po, pl, attb);
        mfma_gemm<<<dim3(LL / 16, 1), 256, 0, stream>>>(
            attb, wpt, nullptr, prj, LL, CC, CC, 0);
        ln_kernel<<<LL, 64, 0, stream>>>(prj, tok, ln1g + l * CC, ln1b + l * CC,
                                         tok, tokb);
    }

    mfma_gemm<<<dim3(LL / 16, 4), 256, 0, stream>>>(tokb, w1t, b1, hdn, LL, CC, 4 * CC, 1 | 2);
    mfma_gemm<<<dim3(LL / 16, 1), 256, 0, stream>>>(hdn, w2t, b2, prj, LL, 4 * CC, CC, 0);
    ln_kernel<<<LL, 64, 0, stream>>>(prj, tok, ln2g, ln2b, tok, tokb);

    detok_kernel<<<2000, 256, 0, stream>>>(tok, out);
}

// Round 7
// 122.489 us; speedup vs baseline: 2.2114x; 1.9863x over previous
//
#include <hip/hip_runtime.h>
#include <hip/hip_bf16.h>
#include <math.h>

// Problem constants: S=4, B=1, C=128, h=w=d=10 -> N=1000, L=4000, nL=2, H=8, Dh=16
#define LL 4000
#define CC 128
#define NN 1000
#define NLAYER 2
#define KSPLIT 4                        // == S; split-K aligned to sequences
#define SCLOG2 0.36067376022224085f    // 0.25 * log2(e), folded into Q
#define KROW 20                        // padded LDS row (shorts) for K tile [32][KROW]
#define VROW 36                        // padded LDS row (shorts) for V^T tile [16][VROW]

typedef __attribute__((ext_vector_type(4))) short bf16x4;
typedef __attribute__((ext_vector_type(8))) short short8;
typedef __attribute__((ext_vector_type(4))) float f32x4;
typedef __attribute__((ext_vector_type(2))) unsigned int u32x2;

__device__ __forceinline__ short bf16rne(float f) {
    return __builtin_bit_cast(short, __float2bfloat16(f));
}

// pack 4 f32 -> 4 bf16 (truncate) via 2x v_perm_b32
__device__ __forceinline__ bf16x4 pack4(const float* p) {
    unsigned w01 = __builtin_amdgcn_perm(__builtin_bit_cast(unsigned, p[1]),
                                         __builtin_bit_cast(unsigned, p[0]),
                                         0x07060302u);
    unsigned w23 = __builtin_amdgcn_perm(__builtin_bit_cast(unsigned, p[3]),
                                         __builtin_bit_cast(unsigned, p[2]),
                                         0x07060302u);
    u32x2 w = {w01, w23};
    return __builtin_bit_cast(bf16x4, w);
}

// ---------------------------------------------------------------------------
// tokenize: z[S,1,C,N] + seq_embed[S,C] -> tok[L,C] (f32) + tokb (bf16)
__global__ void tokenize_kernel(const float* __restrict__ z,
                                const float* __restrict__ se,
                                float* __restrict__ tok,
                                short* __restrict__ tokb) {
    int idx = blockIdx.x * blockDim.x + threadIdx.x;
    if (idx >= LL * CC) return;
    int c = idx & (CC - 1);
    int t = idx >> 7;
    int s = t / NN;
    int n = t - s * NN;
    float v = z[(s * CC + c) * NN + n] + se[s * CC + c];
    tok[idx] = v;
    tokb[idx] = bf16rne(v);
}

// detokenize: tok[L,C] -> out[(s*C+c)*N + n]
__global__ void detok_kernel(const float* __restrict__ tok,
                             float* __restrict__ out) {
    int idx = blockIdx.x * blockDim.x + threadIdx.x;
    if (idx >= LL * CC) return;
    int n = idx % NN;
    int sc = idx / NN;
    int c = sc & (CC - 1);
    int s = sc >> 7;
    out[idx] = tok[(s * NN + n) * CC + c];
}

// kbw[l*KSPLIT+z] = r[z]^beta[l]  (per-sequence softmax weight; row term of
// log R is softmax-invariant, clamp inactive since r>=0.1)
__global__ void kbw_kernel(const float* __restrict__ r,
                           const float* __restrict__ beta,
                           float* __restrict__ kbw) {
    int idx = threadIdx.x;
    if (idx >= NLAYER * KSPLIT) return;
    int l = idx / KSPLIT;
    int z = idx - l * KSPLIT;
    kbw[idx] = exp2f(beta[l] * __log2f(r[z]));
}

// ---------------------------------------------------------------------------
// weight prep: bf16 + transpose -> Wt[N][K]
__global__ void prep_weights(const float* __restrict__ Wq, const float* __restrict__ Wk,
                             const float* __restrict__ Wv, const float* __restrict__ Wp,
                             const float* __restrict__ w1, const float* __restrict__ w2,
                             short* __restrict__ wt8, short* __restrict__ w1t,
                             short* __restrict__ w2t) {
    int idx = blockIdx.x * blockDim.x + threadIdx.x;
    if (idx < 8 * 16384) {
        int m = idx >> 14, i = idx & 16383;
        int n = i >> 7, k = i & 127;
        const float* src = (m < 2) ? Wq + (size_t)m * 16384
                         : (m < 4) ? Wk + (size_t)(m - 2) * 16384
                         : (m < 6) ? Wv + (size_t)(m - 4) * 16384
                                   : Wp + (size_t)(m - 6) * 16384;
        wt8[idx] = bf16rne(src[k * 128 + n]);
    } else if (idx < 8 * 16384 + 65536) {
        int i = idx - 8 * 16384;
        int n = i >> 7, k = i & 127;
        w1t[i] = bf16rne(w1[(size_t)k * 512 + n]);
    } else if (idx < 8 * 16384 + 2 * 65536) {
        int i = idx - 8 * 16384 - 65536;
        int n = i >> 9, k = i & 511;
        w2t[i] = bf16rne(w2[(size_t)k * 128 + n]);
    }
}

// ---------------------------------------------------------------------------
// MFMA GEMM body: out[M,N] = act(A[M,K] @ Wt[N,K]^T + bias)
// flags: 1 = bf16 out, 2 = exact GELU, 4 = bf16 transposed out [N][M],
//        8 = *SCLOG2, 16 = bf16 head-major out [N/16][M][16]
__device__ __forceinline__ void gemm_body(
        const short* __restrict__ A, const short* __restrict__ Wt,
        const float* __restrict__ bias, void* __restrict__ outp,
        int M, int K, int N, int flags, int row0, int col0) {
    __shared__ short Al[16][136];
    __shared__ short Wl[128][136];
    const int tid = threadIdx.x;
    const int lane = tid & 63;
    const int w = tid >> 6;
    const int lq = lane & 15, g = lane >> 4;

    f32x4 acc[2] = {{0.f,0.f,0.f,0.f},{0.f,0.f,0.f,0.f}};

    for (int kc = 0; kc < K; kc += 128) {
        {
            int r = tid >> 4, c = (tid & 15) * 8;
            *(short8*)&Al[r][c] = *(const short8*)(A + (size_t)(row0 + r) * K + kc + c);
        }
        {
            int c = (tid & 15) * 8;
            int nb = tid >> 4;
            #pragma unroll
            for (int i = 0; i < 8; ++i) {
                int n = nb + i * 16;
                *(short8*)&Wl[n][c] = *(const short8*)(Wt + (size_t)(col0 + n) * K + kc + c);
            }
        }
        __syncthreads();
        bf16x4 af[8];
        #pragma unroll
        for (int ks = 0; ks < 8; ++ks)
            af[ks] = *(const bf16x4*)&Al[lq][ks * 16 + g * 4];
        #pragma unroll
        for (int ct = 0; ct < 2; ++ct) {
            int n = (w * 2 + ct) * 16 + lq;
            #pragma unroll
            for (int ks = 0; ks < 8; ++ks) {
                bf16x4 bfr = *(const bf16x4*)&Wl[n][ks * 16 + g * 4];
                acc[ct] = __builtin_amdgcn_mfma_f32_16x16x16bf16_1k(af[ks], bfr, acc[ct], 0, 0, 0);
            }
        }
        __syncthreads();
    }
    #pragma unroll
    for (int ct = 0; ct < 2; ++ct) {
        int col = col0 + (w * 2 + ct) * 16 + lq;
        float bv = bias ? bias[col] : 0.f;
        float v[4];
        #pragma unroll
        for (int r = 0; r < 4; ++r) {
            v[r] = acc[ct][r] + bv;
            if (flags & 2) v[r] = 0.5f * v[r] * (1.f + erff(v[r] * 0.70710678118654752f));
            if (flags & 8) v[r] *= SCLOG2;
        }
        if (flags & 4) {
            bf16x4 res = {bf16rne(v[0]), bf16rne(v[1]), bf16rne(v[2]), bf16rne(v[3])};
            *(bf16x4*)((short*)outp + (size_t)col * M + row0 + g * 4) = res;
        } else if (flags & 16) {   // head-major [H][M][16]
            #pragma unroll
            for (int r = 0; r < 4; ++r)
                ((short*)outp)[((size_t)(col >> 4) * M + (row0 + g * 4 + r)) * 16 + (col & 15)] = bf16rne(v[r]);
        } else if (flags & 1) {
            #pragma unroll
            for (int r = 0; r < 4; ++r)
                ((short*)outp)[(size_t)(row0 + g * 4 + r) * N + col] = bf16rne(v[r]);
        } else {
            #pragma unroll
            for (int r = 0; r < 4; ++r)
                ((float*)outp)[(size_t)(row0 + g * 4 + r) * N + col] = v[r];
        }
    }
}

__global__ __launch_bounds__(256) void mfma_gemm(
        const short* __restrict__ A, const short* __restrict__ Wt,
        const float* __restrict__ bias, void* __restrict__ outp,
        int M, int K, int N, int flags) {
    gemm_body(A, Wt, bias, outp, M, K, N, flags,
              blockIdx.x * 16, blockIdx.y * 128);
}

// fused QKV: z=0 Q (bf16, *SCLOG2), z=1 K (head-major [H][L][16]), z=2 V^T [C][L]
__global__ __launch_bounds__(256) void mfma_gemm3(
        const short* __restrict__ A,
        const short* __restrict__ W0, const short* __restrict__ W1,
        const short* __restrict__ W2,
        short* __restrict__ o0, short* __restrict__ o1, short* __restrict__ o2,
        int M, int K, int N) {
    const short* Wt = (blockIdx.z == 0) ? W0 : (blockIdx.z == 1) ? W1 : W2;
    short* o = (blockIdx.z == 0) ? o0 : (blockIdx.z == 1) ? o1 : o2;
    int flags = (blockIdx.z == 0) ? (1 | 8) : (blockIdx.z == 1) ? 16 : 4;
    gemm_body(A, Wt, nullptr, o, M, K, N, flags, blockIdx.x * 16, 0);
}

// ---------------------------------------------------------------------------
// MFMA flash attention, fixed-shift softmax, sequence-aligned split-K,
// LDS-staged K/V tiles shared by 4 waves (4 q-tiles) per block.
// K staged from head-major Kh[H][L][16] (1KB contiguous per 32-key tile);
// V^T staged from Vt[C][L] (16 rows x 64B). Fragments via ds_read_b64 from
// padded LDS rows (<=2-way bank conflicts). Double-buffered, one barrier/tile,
// issue-early/write-late staging (T14).
__global__ __launch_bounds__(256) void attn_mfma_kernel(
        const short* __restrict__ Qb, const short* __restrict__ Kh,
        const short* __restrict__ Vt, const float* __restrict__ kbw,
        float* __restrict__ po, float* __restrict__ pl) {
    __shared__ short Kl[2][32][KROW];
    __shared__ short Vl[2][16][VROW];
    const int tid  = threadIdx.x;
    const int lane = tid & 63;
    const int wv   = tid >> 6;
    const int lq = lane & 15;
    const int g  = lane >> 4;
    const int h  = blockIdx.y;
    const int z  = blockIdx.z;
    const int qt = blockIdx.x * 4 + wv;
    const int q0 = qt * 16;
    const int hd0 = h * 16;
    const int kbase = z * NN;
    const bool qvalid = qt < LL / 16;

    bf16x4 qf = {0, 0, 0, 0};
    if (qvalid) qf = *(const bf16x4*)(Qb + (size_t)(q0 + lq) * CC + hd0 + 4 * g);

    // ones-row A fragment: A[0][k] = 1 -> D[0][q] = sum_k P[k][q]
    const short onev = (lq == 0) ? (short)0x3F80 : (short)0;
    const bf16x4 af1 = {onev, onev, onev, onev};

    // staging addresses (thread-flat across the block)
    const short* kgp = Kh + ((size_t)h * LL + kbase) * 16 + tid * 2;          // + k0*16
    const short* vgp = Vt + (size_t)(hd0 + (tid >> 4)) * LL + kbase + (tid & 15) * 2;  // + k0
    short* kwp = &Kl[0][0][0] + (tid >> 3) * KROW + (tid & 7) * 2;
    short* vwp = &Vl[0][0][0] + (tid >> 4) * VROW + (tid & 15) * 2;
    const int kbufstride = 32 * KROW;
    const int vbufstride = 16 * VROW;

    f32x4 o  = {0.f, 0.f, 0.f, 0.f};
    f32x4 ps = {0.f, 0.f, 0.f, 0.f};

    // prologue: stage tile 0 into buf 0
    {
        unsigned kd = *(const unsigned*)kgp;
        unsigned vd = *(const unsigned*)vgp;
        *(unsigned*)kwp = kd;
        *(unsigned*)vwp = vd;
    }
    __syncthreads();

    for (int t = 0; t < 31; ++t) {
        // issue next tile's global loads early (T14)
        const int k0n = (t + 1) * 32;
        unsigned kd = *(const unsigned*)(kgp + (size_t)k0n * 16);
        unsigned vd = *(const unsigned*)(vgp + k0n);

        // compute tile t from buf t&1
        {
            const short* kb = &Kl[t & 1][0][0];
            const short* vb = &Vl[t & 1][0][0];
            bf16x4 K0 = *(const bf16x4*)(kb + lq * KROW + 4 * g);
            bf16x4 K1 = *(const bf16x4*)(kb + (16 + lq) * KROW + 4 * g);
            bf16x4 V0 = *(const bf16x4*)(vb + lq * VROW + 4 * g);
            bf16x4 V1 = *(const bf16x4*)(vb + lq * VROW + 16 + 4 * g);
            const f32x4 zz = {0.f, 0.f, 0.f, 0.f};
            f32x4 s0 = __builtin_amdgcn_mfma_f32_16x16x16bf16_1k(K0, qf, zz, 0, 0, 0);
            f32x4 s1 = __builtin_amdgcn_mfma_f32_16x16x16bf16_1k(K1, qf, zz, 0, 0, 0);
            float p0[4], p1[4];
            #pragma unroll
            for (int r = 0; r < 4; ++r) {
                p0[r] = __builtin_amdgcn_exp2f(s0[r]);
                p1[r] = __builtin_amdgcn_exp2f(s1[r]);
            }
            bf16x4 pt0 = pack4(p0);
            bf16x4 pt1 = pack4(p1);
            o  = __builtin_amdgcn_mfma_f32_16x16x16bf16_1k(V0, pt0, o, 0, 0, 0);
            o  = __builtin_amdgcn_mfma_f32_16x16x16bf16_1k(V1, pt1, o, 0, 0, 0);
            ps = __builtin_amdgcn_mfma_f32_16x16x16bf16_1k(af1, pt0, ps, 0, 0, 0);
            ps = __builtin_amdgcn_mfma_f32_16x16x16bf16_1k(af1, pt1, ps, 0, 0, 0);
        }

        // write next tile into the other buffer, then barrier
        const int nb = (t + 1) & 1;
        *(unsigned*)(kwp + nb * kbufstride) = kd;
        *(unsigned*)(vwp + nb * vbufstride) = vd;
        __syncthreads();
    }

    {   // tail tile 31: local keys 992..999 valid; mask P (g>=2) AND V-frag
        const short* kb = &Kl[1][0][0];
        const short* vb = &Vl[1][0][0];
        bf16x4 K0 = *(const bf16x4*)(kb + lq * KROW + 4 * g);
        bf16x4 V0 = *(const bf16x4*)(vb + lq * VROW + 4 * g);
        if (g >= 2) V0 = (bf16x4){0, 0, 0, 0};
        const f32x4 zz = {0.f, 0.f, 0.f, 0.f};
        f32x4 s0 = __builtin_amdgcn_mfma_f32_16x16x16bf16_1k(K0, qf, zz, 0, 0, 0);
        float p0[4];
        #pragma unroll
        for (int r = 0; r < 4; ++r)
            p0[r] = (g < 2) ? __builtin_amdgcn_exp2f(s0[r]) : 0.f;
        bf16x4 pt0 = pack4(p0);
        o  = __builtin_amdgcn_mfma_f32_16x16x16bf16_1k(V0, pt0, o, 0, 0, 0);
        ps = __builtin_amdgcn_mfma_f32_16x16x16bf16_1k(af1, pt0, ps, 0, 0, 0);
    }

    if (qvalid) {
        const float wz = kbw[z];
        f32x4 ow = {o[0] * wz, o[1] * wz, o[2] * wz, o[3] * wz};
        *(f32x4*)(po + (size_t)z * LL * CC + (size_t)(q0 + lq) * CC + hd0 + 4 * g) = ow;
        if (g == 0) pl[(z * 8 + h) * LL + q0 + lq] = ps[0] * wz;
    }
}

// combine: attb[q][c] = bf16( sum_z po / sum_z pl )
__global__ void attn_combine(const float* __restrict__ po,
                             const float* __restrict__ pl,
                             short* __restrict__ attb) {
    int i = blockIdx.x * blockDim.x + threadIdx.x;
    if (i >= LL * CC / 4) return;
    int q  = i >> 5;
    int c0 = (i & 31) * 4;
    int h  = c0 >> 4;
    size_t off = (size_t)q * CC + c0;
    f32x4 o = {0.f, 0.f, 0.f, 0.f};
    float l = 0.f;
    #pragma unroll
    for (int zz = 0; zz < KSPLIT; ++zz) {
        f32x4 t = *(const f32x4*)(po + (size_t)zz * LL * CC + off);
        o[0] += t[0]; o[1] += t[1]; o[2] += t[2]; o[3] += t[3];
        l += pl[(zz * 8 + h) * LL + q];
    }
    float inv = 1.f / l;
    bf16x4 res = {bf16rne(o[0] * inv), bf16rne(o[1] * inv),
                  bf16rne(o[2] * inv), bf16rne(o[3] * inv)};
    *(bf16x4*)(attb + off) = res;
}

// ---------------------------------------------------------------------------
// Fused residual-add + LayerNorm over C=128; writes f32 + bf16 copies.
__global__ void ln_kernel(const float* __restrict__ X,
                          const float* __restrict__ R,
                          const float* __restrict__ g,
                          const float* __restrict__ b,
                          float* __restrict__ out,
                          short* __restrict__ outb) {
    int row  = blockIdx.x;
    int lane = threadIdx.x;
    size_t off = (size_t)row * CC;
    float x0 = X[off + lane]      + R[off + lane];
    float x1 = X[off + 64 + lane] + R[off + 64 + lane];
    float s  = x0 + x1;
    float s2 = x0 * x0 + x1 * x1;
    #pragma unroll
    for (int w = 32; w >= 1; w >>= 1) {
        s  += __shfl_xor(s,  w);
        s2 += __shfl_xor(s2, w);
    }
    float mu   = s * (1.f / CC);
    float var  = s2 * (1.f / CC) - mu * mu;
    float rstd = rsqrtf(var + 1e-5f);
    float y0 = (x0 - mu) * rstd * g[lane]      + b[lane];
    float y1 = (x1 - mu) * rstd * g[lane + 64] + b[lane + 64];
    out[off + lane]      = y0;
    out[off + 64 + lane] = y1;
    outb[off + lane]      = bf16rne(y0);
    outb[off + 64 + lane] = bf16rne(y1);
}

// ---------------------------------------------------------------------------
extern "C" void kernel_launch(void* const* d_in, const int* in_sizes, int n_in,
                              void* d_out, int out_size, void* d_ws, size_t ws_size,
                              hipStream_t stream) {
    const float* z    = (const float*)d_in[0];
    const float* r    = (const float*)d_in[1];
    const float* se   = (const float*)d_in[2];
    const float* Wq   = (const float*)d_in[3];
    const float* Wk   = (const float*)d_in[4];
    const float* Wv   = (const float*)d_in[5];
    const float* Wp   = (const float*)d_in[6];
    const float* beta = (const float*)d_in[7];
    const float* ln1g = (const float*)d_in[8];
    const float* ln1b = (const float*)d_in[9];
    const float* w1   = (const float*)d_in[10];
    const float* b1   = (const float*)d_in[11];
    const float* w2   = (const float*)d_in[12];
    const float* b2   = (const float*)d_in[13];
    const float* ln2g = (const float*)d_in[14];
    const float* ln2b = (const float*)d_in[15];
    float* out = (float*)d_out;

    float* ws    = (float*)d_ws;
    float* tok   = ws;                               // 512000 f
    float* prj   = tok + LL * CC;                    // 512000 f
    float* kbw   = prj + LL * CC;                    // 8 f
    float* pl    = kbw + 8;                          // KSPLIT*8*LL f
    float* po    = pl + KSPLIT * 8 * LL;             // KSPLIT*LL*CC f = 8 MB
    short* hdn   = (short*)po;                       // aliased: FFN phase only
    short* tokb  = (short*)(po + (size_t)KSPLIT * LL * CC);
    short* attb  = tokb + LL * CC;
    short* Qb    = attb + LL * CC;
    short* Kh    = Qb   + LL * CC;                   // head-major [H][L][16]
    short* Vt    = Kh   + LL * CC;                   // transposed [C][L]
    short* wt8   = Vt   + LL * CC;
    short* w1t   = wt8  + 8 * 16384;
    short* w2t   = w1t  + 65536;

    prep_weights<<<1024, 256, 0, stream>>>(Wq, Wk, Wv, Wp, w1, w2, wt8, w1t, w2t);
    tokenize_kernel<<<2000, 256, 0, stream>>>(z, se, tok, tokb);
    kbw_kernel<<<1, 64, 0, stream>>>(r, beta, kbw);

    for (int l = 0; l < NLAYER; ++l) {
        const short* wqt = wt8 + (size_t)(0 * 2 + l) * 16384;
        const short* wkt = wt8 + (size_t)(1 * 2 + l) * 16384;
        const short* wvt = wt8 + (size_t)(2 * 2 + l) * 16384;
        const short* wpt = wt8 + (size_t)(3 * 2 + l) * 16384;
        mfma_gemm3<<<dim3(LL / 16, 1, 3), 256, 0, stream>>>(
            tokb, wqt, wkt, wvt, Qb, Kh, Vt, LL, CC, CC);
        attn_mfma_kernel<<<dim3((LL / 16 + 3) / 4, 8, KSPLIT), 256, 0, stream>>>(
            Qb, Kh, Vt, kbw + l * KSPLIT, po, pl);
        attn_combine<<<(LL * CC / 4 + 255) / 256, 256, 0, stream>>>(po, pl, attb);
        mfma_gemm<<<dim3(LL / 16, 1), 256, 0, stream>>>(
            attb, wpt, nullptr, prj, LL, CC, CC, 0);
        ln_kernel<<<LL, 64, 0, stream>>>(prj, tok, ln1g + l * CC, ln1b + l * CC,
                                         tok, tokb);
    }

    mfma_gemm<<<dim3(LL / 16, 4), 256, 0, stream>>>(tokb, w1t, b1, hdn, LL, CC, 4 * CC, 1 | 2);
    mfma_gemm<<<dim3(LL / 16, 1), 256, 0, stream>>>(hdn, w2t, b2, prj, LL, 4 * CC, CC, 0);
    ln_kernel<<<LL, 64, 0, stream>>>(prj, tok, ln2g, ln2b, tok, tokb);

    detok_kernel<<<2000, 256, 0, stream>>>(tok, out);
}